// Round 6
// baseline (247.925 us; speedup 1.0000x reference)
//
#include <hip/hip_runtime.h>
#include <stdint.h>

// RobertaSelfAttention: B=4, S=2048, HID=1024, NH=16, HD=64. fp32 in/out.
// R10:
//  qkv_gemm: R9's 3-buffer counted-vmcnt pipeline, FIXED: the loop barrier
//  is now raw __builtin_amdgcn_s_barrier() (NOT __syncthreads, whose
//  semantics emit s_waitcnt vmcnt(0) and defeated the counted pipeline in
//  R9 -> +13us regression). Per-wave vmcnt(3) before the barrier guarantees
//  stage(s) landed; stages s+1,s+2 stay in flight across it. stage(s+2)
//  issued right after the barrier (max latency window = 2 compute phases).
//  attn_k: Q-tile split 256->128 rows/block (grid 16x64 = 1024 blocks =
//  4 blocks/CU; LDS 4x40960 = exactly 160KiB). R9 counters showed
//  occupancy pinned at 18% by the 512-block grid (2/CU) while VGPR/LDS
//  allow 4/CU; with 2 waves/SIMD the serial softmax couldn't be covered.
//  Each wave now owns one 32-q group (state halves, ~95 VGPR), same total
//  MFMA/VALU per CU, 2x waves/SIMD for overlap.

typedef float f32x4 __attribute__((ext_vector_type(4)));
typedef float f32x16 __attribute__((ext_vector_type(16)));
typedef __bf16 bf16x4 __attribute__((ext_vector_type(4)));
typedef __bf16 bf16x8 __attribute__((ext_vector_type(8)));
typedef unsigned short ushort_t;
typedef uint32_t u32;

#define MFMA16(a, b, c) __builtin_amdgcn_mfma_f32_16x16x32_bf16(a, b, c, 0, 0, 0)
#define MFMA32(a, b, c) __builtin_amdgcn_mfma_f32_32x32x16_bf16(a, b, c, 0, 0, 0)

__device__ __forceinline__ ushort_t f2b(float f) {
    union { float f; uint32_t u; } x{f};
    uint32_t r = (x.u + 0x7fffu + ((x.u >> 16) & 1u)) >> 16;  // RNE
    return (ushort_t)r;
}

__device__ __forceinline__ float fexp2(float x) {
#if __has_builtin(__builtin_amdgcn_exp2f)
    return __builtin_amdgcn_exp2f(x);
#else
    return exp2f(x);
#endif
}

// pack {bf16(e) lo16, bf16(o) hi16} by byte-perm truncation (e,o > 0)
__device__ __forceinline__ u32 pkpair(float e, float o) {
    union { float f; u32 u; } xe{e}, xo{o};
    return __builtin_amdgcn_perm(xo.u, xe.u, 0x07060302u);
}

__device__ __forceinline__ bf16x8 mk8(u32 a, u32 b, u32 c, u32 d) {
    union { u32 u[4]; bf16x8 v; } x;
    x.u[0] = a; x.u[1] = b; x.u[2] = c; x.u[3] = d;
    return x.v;
}

__device__ __forceinline__ bf16x8 cat8(bf16x4 a, bf16x4 b) {
    return __builtin_shufflevector(a, b, 0, 1, 2, 3, 4, 5, 6, 7);
}

__device__ __forceinline__ void gld_lds16(const void* g, void* l) {
    __builtin_amdgcn_global_load_lds(
        (const __attribute__((address_space(1))) unsigned int*)g,
        (__attribute__((address_space(3))) unsigned int*)l, 16, 0, 0);
}

// ---------------- fp32 -> bf16 convert: hidden (8M) + Wq/Wk/Wv (3x1M) -------
__global__ __launch_bounds__(256) void convert_k(
    const float* __restrict__ hs, const float* __restrict__ wq,
    const float* __restrict__ wk, const float* __restrict__ wv,
    ushort_t* __restrict__ hs_b, ushort_t* __restrict__ w_b) {
    size_t c = (size_t)blockIdx.x * 256 + threadIdx.x;
    size_t i = c * 8;
    const size_t NHS = (size_t)8192 * 1024;
    const float* src;
    ushort_t* dst;
    if (i < NHS) { src = hs + i; dst = hs_b + i; }
    else {
        size_t j = i - NHS;
        int w = (int)(j >> 20);
        size_t o = j & ((1u << 20) - 1);
        src = (w == 0 ? wq : (w == 1 ? wk : wv)) + o;
        dst = w_b + ((size_t)w << 20) + o;
    }
    float4 a = *(const float4*)src;
    float4 b = *(const float4*)(src + 4);
    uint32_t p0 = (uint32_t)f2b(a.x) | ((uint32_t)f2b(a.y) << 16);
    uint32_t p1 = (uint32_t)f2b(a.z) | ((uint32_t)f2b(a.w) << 16);
    uint32_t p2 = (uint32_t)f2b(b.x) | ((uint32_t)f2b(b.y) << 16);
    uint32_t p3 = (uint32_t)f2b(b.z) | ((uint32_t)f2b(b.w) << 16);
    uint4 v{p0, p1, p2, p3};
    *(uint4*)dst = v;
}

// ---------------- QKV projection GEMM: 3-buffer pipeline, raw barrier -------
// 768 blocks: lid=(bid&7)*96+bid/8; which=lid>>8; m=(lid&255)>>3; n=lid&7.
// Buffers: 3 x { At[256][32] (16KB) + Bt[128][32] (8KB) } = 72KB. Stage = 3
// gld_lds/lane. Loop step s: vmcnt(3) [stage(s) landed; s+1,s+2 in flight],
// raw s_barrier, issue stage(s+2), ds_read+MFMA buf(s%3). Race-free: all
// waves' reads of buf(s-1) completed before the iter-s barrier (consumed by
// MFMAs pre-barrier); stage(s+2) writes that buffer post-barrier.
__global__ __launch_bounds__(512, 4) void qkv_gemm(
    const ushort_t* __restrict__ Ab, const ushort_t* __restrict__ Wb,
    const float* __restrict__ bq, const float* __restrict__ bk,
    const float* __restrict__ bv, ushort_t* __restrict__ q_ws,
    ushort_t* __restrict__ k_ws, ushort_t* __restrict__ vt_ws) {
    __shared__ __align__(16) char smem_raw[73728];  // 3 x 24576
    ushort_t* Ct = (ushort_t*)smem_raw;             // epilogue overlay [128][136]

    int bid = blockIdx.x;
    int lid = (bid & 7) * 96 + (bid >> 3);
    int which = lid >> 8;
    int rem = lid & 255;
    int m0 = (rem >> 3) * 256, n0 = (rem & 7) * 128;
    const ushort_t* W = Wb + ((size_t)which << 20);

    int t = threadIdx.x, lane = t & 63, wave = t >> 6;
    int quad = lane >> 4, l16 = lane & 15;
    int wm = wave >> 1, wn = wave & 1;
    int wr = wm * 64, wc = wn * 64;
    f32x4 acc[4][4] = {};

    // stage K-tile k (k0 = k*32) into buffer buf
    auto stage = [&](int buf, int k) {
        int k0 = k * 32;
        ushort_t* At = (ushort_t*)smem_raw + buf * 12288;
        ushort_t* Bt = At + 8192;
#pragma unroll
        for (int r = 0; r < 2; r++) {
            int idx = r * 512 + t;
            int row = idx >> 2, ch = idx & 3;
            int sch = (ch ^ ((row >> 1) & 3)) * 8;
            gld_lds16(Ab + (size_t)(m0 + row) * 1024 + k0 + sch, At + idx * 8);
        }
        {
            int idx = t;
            int row = idx >> 2, ch = idx & 3;
            int sch = (ch ^ ((row >> 1) & 3)) * 8;
            gld_lds16(W + (size_t)(n0 + row) * 1024 + k0 + sch, Bt + idx * 8);
        }
    };

    stage(0, 0);
    stage(1, 1);
    int cur = 0;

    for (int s = 0; s < 32; s++) {
        if (s == 31) asm volatile("s_waitcnt vmcnt(0)" ::: "memory");
        else         asm volatile("s_waitcnt vmcnt(3)" ::: "memory");
        __builtin_amdgcn_s_barrier();             // raw: no implicit vmcnt(0)
        __builtin_amdgcn_sched_barrier(0);
        if (s + 2 < 32) stage(cur >= 1 ? cur - 1 : 2, s + 2);  // (cur+2)%3
        const ushort_t* At = (const ushort_t*)smem_raw + cur * 12288;
        const ushort_t* Bt = At + 8192;
        bf16x8 af[4], bf[4];
#pragma unroll
        for (int i = 0; i < 4; i++) {
            int r = wr + i * 16 + l16;
            af[i] = *(const bf16x8*)(At + r * 32 + ((quad ^ ((r >> 1) & 3)) * 8));
        }
#pragma unroll
        for (int j = 0; j < 4; j++) {
            int r = wc + j * 16 + l16;
            bf[j] = *(const bf16x8*)(Bt + r * 32 + ((quad ^ ((r >> 1) & 3)) * 8));
        }
#pragma unroll
        for (int i = 0; i < 4; i++)
#pragma unroll
            for (int j = 0; j < 4; j++)
                acc[i][j] = MFMA16(af[i], bf[j], acc[i][j]);
        cur = cur < 2 ? cur + 1 : 0;
    }
    __syncthreads();  // full drain before epilogue overlays buffers

    const float* bias = which == 0 ? bq : (which == 1 ? bk : bv);
    float sc = which == 0 ? (0.125f * 1.44269504f) : 1.0f;  // 1/sqrt(HD)*log2e
#pragma unroll
    for (int mh = 0; mh < 2; mh++) {
        bool mine = (wm >> 1) == mh;
        int mrel = wr - mh * 128;  // 0 or 64 when mine
        if (which == 2) {
            if (mine) {
                for (int j = 0; j < 4; j++) {
                    float bias_v = bias[n0 + wc + j * 16 + l16];
                    int nrow = wc + j * 16 + l16;
                    for (int i = 0; i < 4; i++) {
                        ushort4 pk;
                        pk.x = f2b(acc[i][j].x + bias_v);
                        pk.y = f2b(acc[i][j].y + bias_v);
                        pk.z = f2b(acc[i][j].z + bias_v);
                        pk.w = f2b(acc[i][j].w + bias_v);
                        *(ushort4*)(Ct + nrow * 136 + mrel + i * 16 + quad * 4) = pk;
                    }
                }
            }
        } else {
            if (mine) {
                for (int j = 0; j < 4; j++) {
                    float bias_v = bias[n0 + wc + j * 16 + l16];
                    int col = wc + j * 16 + l16;
                    for (int i = 0; i < 4; i++) {
                        int rb = mrel + i * 16 + quad * 4;
                        Ct[(rb + 0) * 136 + col] = f2b((acc[i][j].x + bias_v) * sc);
                        Ct[(rb + 1) * 136 + col] = f2b((acc[i][j].y + bias_v) * sc);
                        Ct[(rb + 2) * 136 + col] = f2b((acc[i][j].z + bias_v) * sc);
                        Ct[(rb + 3) * 136 + col] = f2b((acc[i][j].w + bias_v) * sc);
                    }
                }
            }
        }
        __syncthreads();
#pragma unroll
        for (int it = 0; it < 4; it++) {
            int c = it * 512 + t;
            int row = c >> 4, c8 = (c & 15) * 8;
            uint4 val = *(const uint4*)(Ct + row * 136 + c8);
            if (which == 2) {
                int col = n0 + row, h = col >> 6, d = col & 63;
                int tok = m0 + mh * 128 + c8, b = tok >> 11, s = tok & 2047;
                *(uint4*)(vt_ws + ((size_t)(b * 16 + h) * 64 + d) * 2048 + s) = val;
            } else {
                int tok = m0 + mh * 128 + row, b = tok >> 11, s = tok & 2047;
                int col = n0 + c8, h = col >> 6, d = col & 63;
                ushort_t* base = which == 0 ? q_ws : k_ws;
                *(uint4*)(base + ((size_t)(b * 16 + h) * 2048 + s) * 64 + d) = val;
            }
        }
        __syncthreads();
    }
}

// ---------------- flash attention: 128 q/block, 4 blocks/CU -----------------
// Grid (16 q-tiles, 64 bh). Block = 4 waves x 32 q. Wave owns one 32-q
// group: S^T C-frag col=q=lane&31, row=key=(reg&3)+8*(reg>>2)+4*(lane>>5).
// kappa-permuted PV (both operands, lane-local P^T frags). K/V dbuf + LDS
// mask unchanged (R6-verified). LDS 40960 -> exactly 4 blocks/CU.
__global__ __launch_bounds__(256, 4) void attn_k(
    const ushort_t* __restrict__ q_ws, const ushort_t* __restrict__ k_ws,
    const ushort_t* __restrict__ vt_ws, const float* __restrict__ mask,
    float* __restrict__ out) {
    __shared__ __align__(16) char smraw[40960];  // 2x16KB K/V dbuf + 8KB mask
    float* Ow = (float*)smraw;                   // epilogue overlay [128][65]
    const float* Mf = (const float*)(smraw + 32768);  // mask row [2048] f32

    int bh = blockIdx.y, b = bh >> 4, h = bh & 15;
    int q0 = blockIdx.x * 128;
    int t = threadIdx.x, lane = t & 63, w = t >> 6;
    int l31 = lane & 31, hi = lane >> 5;
    const ushort_t* Q = q_ws + (size_t)bh * 2048 * 64;
    const ushort_t* K = k_ws + (size_t)bh * 2048 * 64;
    const ushort_t* Vt = vt_ws + (size_t)bh * 64 * 2048;
    const float* mrow = mask + b * 2048;

    bf16x8 qf[4];
#pragma unroll
    for (int cs = 0; cs < 4; cs++)
        qf[cs] = *(const bf16x8*)(
            Q + (size_t)(q0 + w * 32 + l31) * 64 + cs * 16 + hi * 8);
    int co[4];
#pragma unroll
    for (int cs = 0; cs < 4; cs++) co[cs] = ((cs * 2 + hi) ^ (l31 & 7)) * 8;

    f32x16 o00 = {}, o01 = {};
    float rs0 = 0.f;

    auto stage = [&](int buf, int t0) {
        ushort_t* Kb = (ushort_t*)smraw + buf * 8192;  // 16384 B per buffer
#pragma unroll
        for (int it = 0; it < 2; it++) {
            int idx = it * 256 + t;
            int row = idx >> 3, ch = idx & 7;
            int sch = (ch ^ (row & 7)) * 8;
            gld_lds16(K + (size_t)(t0 + row) * 64 + sch, Kb + idx * 8);
            gld_lds16(Vt + (size_t)row * 2048 + t0 + sch, Kb + 4096 + idx * 8);
        }
    };

    // prologue: stage mask row (8KB) + first K/V tile
    {
        char* Mb = smraw + 32768;
#pragma unroll
        for (int it = 0; it < 2; it++) {
            int idx = it * 256 + t;
            gld_lds16(mrow + idx * 4, Mb + idx * 16);
        }
    }
    stage(0, 0);
    asm volatile("s_waitcnt vmcnt(0)" ::: "memory");
    __syncthreads();
    int cur = 0;

    for (int t0 = 0; t0 < 2048; t0 += 64) {
        if (t0 + 64 < 2048) stage(cur ^ 1, t0 + 64);  // prefetch next tile
        const ushort_t* Kl = (const ushort_t*)smraw + cur * 8192;
        const ushort_t* Vtl = Kl + 4096;

        // S^T = K · Q^T
        f32x16 s00 = {}, s01 = {};
#pragma unroll
        for (int cs = 0; cs < 4; cs++) {
            bf16x8 k0 = *(const bf16x8*)(Kl + l31 * 64 + co[cs]);
            bf16x8 k1 = *(const bf16x8*)(Kl + (32 + l31) * 64 + co[cs]);
            s00 = MFMA32(k0, qf[cs], s00);
            s01 = MFMA32(k1, qf[cs], s01);
        }

        // exp2 + pack; P^T B-frags lane-local under kappa permutation.
        u32 pa[8], pb[8];
        {
            float rst = 0.f;
#pragma unroll
            for (int i = 0; i < 4; i++) {
                float4 bm = *(const float4*)(Mf + t0 + 8 * i + 4 * hi);
                float e0 = fexp2(fmaf(bm.x, 1.44269504f, s00[4 * i + 0]));
                float e1 = fexp2(fmaf(bm.y, 1.44269504f, s00[4 * i + 1]));
                float e2 = fexp2(fmaf(bm.z, 1.44269504f, s00[4 * i + 2]));
                float e3 = fexp2(fmaf(bm.w, 1.44269504f, s00[4 * i + 3]));
                rst += (e0 + e1) + (e2 + e3);
                pa[2 * i] = pkpair(e0, e1);
                pa[2 * i + 1] = pkpair(e2, e3);
            }
#pragma unroll
            for (int i = 0; i < 4; i++) {
                float4 bm = *(const float4*)(Mf + t0 + 32 + 8 * i + 4 * hi);
                float e0 = fexp2(fmaf(bm.x, 1.44269504f, s01[4 * i + 0]));
                float e1 = fexp2(fmaf(bm.y, 1.44269504f, s01[4 * i + 1]));
                float e2 = fexp2(fmaf(bm.z, 1.44269504f, s01[4 * i + 2]));
                float e3 = fexp2(fmaf(bm.w, 1.44269504f, s01[4 * i + 3]));
                rst += (e0 + e1) + (e2 + e3);
                pb[2 * i] = pkpair(e0, e1);
                pb[2 * i + 1] = pkpair(e2, e3);
            }
            rs0 += rst;
        }
        bf16x8 pfr[4];
        pfr[0] = mk8(pa[0], pa[1], pa[2], pa[3]);
        pfr[1] = mk8(pa[4], pa[5], pa[6], pa[7]);
        pfr[2] = mk8(pb[0], pb[1], pb[2], pb[3]);
        pfr[3] = mk8(pb[4], pb[5], pb[6], pb[7]);

        // O^T += V^T · P^T (kappa order on both operands)
#pragma unroll
        for (int cs = 0; cs < 4; cs++) {
            int b0 = ((2 * cs) ^ (l31 & 7)) * 8 + 4 * hi;
            int b1 = ((2 * cs + 1) ^ (l31 & 7)) * 8 + 4 * hi;
            bf16x8 v0 = cat8(*(const bf16x4*)(Vtl + l31 * 64 + b0),
                             *(const bf16x4*)(Vtl + l31 * 64 + b1));
            bf16x8 v1 = cat8(*(const bf16x4*)(Vtl + (32 + l31) * 64 + b0),
                             *(const bf16x4*)(Vtl + (32 + l31) * 64 + b1));
            o00 = MFMA32(v0, pfr[cs], o00);
            o01 = MFMA32(v1, pfr[cs], o01);
        }

        asm volatile("s_waitcnt vmcnt(0)" ::: "memory");
        __syncthreads();
        cur ^= 1;
    }
    rs0 += __shfl_xor(rs0, 32, 64);
    float inv0 = 1.f / rs0;
    // epilogue: O^T -> LDS transpose -> coalesced f32x4 stores. Ow row =
    // w*32 + l31 = q offset within block's 128 rows; cols 0-31 from o00,
    // 32-63 from o01.
#pragma unroll
    for (int g = 0; g < 4; g++) {
        f32x4 c0, c1;
#pragma unroll
        for (int r = 0; r < 4; r++) {
            c0[r] = o00[4 * g + r] * inv0;
            c1[r] = o01[4 * g + r] * inv0;
        }
        *(f32x4*)(Ow + (w * 32 + l31) * 65 + 8 * g + 4 * hi) = c0;
        *(f32x4*)(Ow + (w * 32 + l31) * 65 + 32 + 8 * g + 4 * hi) = c1;
    }
    __syncthreads();
#pragma unroll
    for (int cc = 0; cc < 8; cc++) {
        int c = cc * 256 + t;
        int row = c >> 4, seg = (c & 15) * 4;
        f32x4 vv = *(const f32x4*)(Ow + row * 65 + seg);
        *(f32x4*)(out + ((size_t)(b * 2048 + q0 + row)) * 1024 + h * 64 + seg) = vv;
    }
}

extern "C" void kernel_launch(void* const* d_in, const int* in_sizes, int n_in,
                              void* d_out, int out_size, void* d_ws, size_t ws_size,
                              hipStream_t stream) {
    const float* hs = (const float*)d_in[0];
    const float* mask = (const float*)d_in[1];
    const float* wq = (const float*)d_in[2];
    const float* bq = (const float*)d_in[3];
    const float* wk = (const float*)d_in[4];
    const float* bk = (const float*)d_in[5];
    const float* wv = (const float*)d_in[6];
    const float* bv = (const float*)d_in[7];
    float* out = (float*)d_out;
    char* ws = (char*)d_ws;
    ushort_t* hs_b = (ushort_t*)ws;
    ushort_t* w_b = (ushort_t*)(ws + 16777216);
    ushort_t* q_ws = (ushort_t*)(ws + 23068672);
    ushort_t* k_ws = (ushort_t*)(ws + 39845888);
    ushort_t* vt_ws = (ushort_t*)(ws + 56623104);

    convert_k<<<5632, 256, 0, stream>>>(hs, wq, wk, wv, hs_b, w_b);
    qkv_gemm<<<768, 512, 0, stream>>>(hs_b, w_b, bq, bk, bv, q_ws, k_ws, vt_ws);
    attn_k<<<dim3(16, 64), 256, 0, stream>>>(q_ws, k_ws, vt_ws, mask, out);
}

// Round 7
// 239.701 us; speedup vs baseline: 1.0343x; 1.0343x over previous
//
#include <hip/hip_runtime.h>
#include <stdint.h>

// RobertaSelfAttention: B=4, S=2048, HID=1024, NH=16, HD=64. fp32 in/out.
// R11:
//  attn_k: REVERT to R6 (measured 92.4us). R10's 128q split halved K/V
//  amortization (conflicts 2x, MfmaUtil down) -- occupancy was not the lever.
//  qkv_gemm: R7's proven 128^2 tile + epilogue, K-loop upgraded to the
//  R10-validated counted pipeline: BK=32, 3 rotating buffers (48KB LDS ->
//  3 blocks/CU = 12 waves/CU vs R7's 8), per-wave vmcnt(4) + raw s_barrier
//  (no __syncthreads drain in-loop), stage(s+2) issued post-barrier so each
//  stage has ~2 compute phases to land. Same staged bytes/swizzle/grid as R7.

typedef float f32x4 __attribute__((ext_vector_type(4)));
typedef float f32x16 __attribute__((ext_vector_type(16)));
typedef __bf16 bf16x4 __attribute__((ext_vector_type(4)));
typedef __bf16 bf16x8 __attribute__((ext_vector_type(8)));
typedef unsigned short ushort_t;
typedef uint32_t u32;

#define MFMA16(a, b, c) __builtin_amdgcn_mfma_f32_16x16x32_bf16(a, b, c, 0, 0, 0)
#define MFMA32(a, b, c) __builtin_amdgcn_mfma_f32_32x32x16_bf16(a, b, c, 0, 0, 0)

__device__ __forceinline__ ushort_t f2b(float f) {
    union { float f; uint32_t u; } x{f};
    uint32_t r = (x.u + 0x7fffu + ((x.u >> 16) & 1u)) >> 16;  // RNE
    return (ushort_t)r;
}

__device__ __forceinline__ float fexp2(float x) {
#if __has_builtin(__builtin_amdgcn_exp2f)
    return __builtin_amdgcn_exp2f(x);
#else
    return exp2f(x);
#endif
}

// pack {bf16(e) lo16, bf16(o) hi16} by byte-perm truncation (e,o > 0)
__device__ __forceinline__ u32 pkpair(float e, float o) {
    union { float f; u32 u; } xe{e}, xo{o};
    return __builtin_amdgcn_perm(xo.u, xe.u, 0x07060302u);
}

__device__ __forceinline__ bf16x8 mk8(u32 a, u32 b, u32 c, u32 d) {
    union { u32 u[4]; bf16x8 v; } x;
    x.u[0] = a; x.u[1] = b; x.u[2] = c; x.u[3] = d;
    return x.v;
}

__device__ __forceinline__ bf16x8 cat8(bf16x4 a, bf16x4 b) {
    return __builtin_shufflevector(a, b, 0, 1, 2, 3, 4, 5, 6, 7);
}

__device__ __forceinline__ void gld_lds16(const void* g, void* l) {
    __builtin_amdgcn_global_load_lds(
        (const __attribute__((address_space(1))) unsigned int*)g,
        (__attribute__((address_space(3))) unsigned int*)l, 16, 0, 0);
}

// ---------------- fp32 -> bf16 convert: hidden (8M) + Wq/Wk/Wv (3x1M) -------
__global__ __launch_bounds__(256) void convert_k(
    const float* __restrict__ hs, const float* __restrict__ wq,
    const float* __restrict__ wk, const float* __restrict__ wv,
    ushort_t* __restrict__ hs_b, ushort_t* __restrict__ w_b) {
    size_t c = (size_t)blockIdx.x * 256 + threadIdx.x;
    size_t i = c * 8;
    const size_t NHS = (size_t)8192 * 1024;
    const float* src;
    ushort_t* dst;
    if (i < NHS) { src = hs + i; dst = hs_b + i; }
    else {
        size_t j = i - NHS;
        int w = (int)(j >> 20);
        size_t o = j & ((1u << 20) - 1);
        src = (w == 0 ? wq : (w == 1 ? wk : wv)) + o;
        dst = w_b + ((size_t)w << 20) + o;
    }
    float4 a = *(const float4*)src;
    float4 b = *(const float4*)(src + 4);
    uint32_t p0 = (uint32_t)f2b(a.x) | ((uint32_t)f2b(a.y) << 16);
    uint32_t p1 = (uint32_t)f2b(a.z) | ((uint32_t)f2b(a.w) << 16);
    uint32_t p2 = (uint32_t)f2b(b.x) | ((uint32_t)f2b(b.y) << 16);
    uint32_t p3 = (uint32_t)f2b(b.z) | ((uint32_t)f2b(b.w) << 16);
    uint4 v{p0, p1, p2, p3};
    *(uint4*)dst = v;
}

// ---------------- QKV GEMM: 128^2, BK=32, 3-buffer counted-vmcnt ------------
// Grid (64 m, 8 n, 3 which), 256 threads (4 waves, 2x2 of 64x64), acc 4x4.
// LDS 3 x {At[128x32] 8KB + Bt[128x32] 8KB} = 49152 B -> 3 blocks/CU.
// Stage = 4 gld_lds16/thread. Step s: vmcnt(4) [stage(s) done, stage(s+1)
// in flight], raw s_barrier (publishes all waves' stage(s)), issue
// stage(s+2) into buf(s-1) (its last reads completed before this barrier),
// ds_read+MFMA buf(s). Swizzle: 16B chunk ch ^ ((row>>1)&3), both sides.
__global__ __launch_bounds__(256, 3) void qkv_gemm(
    const ushort_t* __restrict__ Ab, const ushort_t* __restrict__ Wb,
    const float* __restrict__ bq, const float* __restrict__ bk,
    const float* __restrict__ bv, ushort_t* __restrict__ q_ws,
    ushort_t* __restrict__ k_ws, ushort_t* __restrict__ vt_ws) {
    __shared__ __align__(16) char smem_raw[49152];  // 3 x 16384
    ushort_t* Ct = (ushort_t*)smem_raw;             // epilogue overlay [128][136]

    int which = blockIdx.z;
    const ushort_t* W = Wb + ((size_t)which << 20);
    int m0 = blockIdx.x * 128, n0 = blockIdx.y * 128;
    int t = threadIdx.x, lane = t & 63, wave = t >> 6;
    int quad = lane >> 4, l16 = lane & 15;
    int wr = (wave >> 1) * 64, wc = (wave & 1) * 64;
    f32x4 acc[4][4] = {};

    // stage K-slice k (k0=k*32) into buffer buf (16384 B each)
    auto stage = [&](int buf, int k) {
        int k0 = k * 32;
        ushort_t* At = (ushort_t*)smem_raw + buf * 8192;  // elem offsets
        ushort_t* Bt = At + 4096;
#pragma unroll
        for (int r = 0; r < 2; r++) {
            int idx = r * 256 + t;               // 512 chunks of 16B each
            int row = idx >> 2, ch = idx & 3;
            int sch = (ch ^ ((row >> 1) & 3)) * 8;
            gld_lds16(Ab + (size_t)(m0 + row) * 1024 + k0 + sch, At + idx * 8);
            gld_lds16(W + (size_t)(n0 + row) * 1024 + k0 + sch, Bt + idx * 8);
        }
    };

    stage(0, 0);
    stage(1, 1);
    int cur = 0;

    for (int s = 0; s < 32; s++) {
        if (s == 31) asm volatile("s_waitcnt vmcnt(0)" ::: "memory");
        else         asm volatile("s_waitcnt vmcnt(4)" ::: "memory");
        __builtin_amdgcn_s_barrier();            // raw: no implicit drain
        __builtin_amdgcn_sched_barrier(0);
        if (s + 2 < 32) stage(cur >= 1 ? cur - 1 : 2, s + 2);  // (cur+2)%3
        const ushort_t* At = (const ushort_t*)smem_raw + cur * 8192;
        const ushort_t* Bt = At + 4096;
        bf16x8 af[4], bf[4];
#pragma unroll
        for (int i = 0; i < 4; i++) {
            int r = wr + i * 16 + l16;
            af[i] = *(const bf16x8*)(At + r * 32 + ((quad ^ ((r >> 1) & 3)) * 8));
        }
#pragma unroll
        for (int j = 0; j < 4; j++) {
            int r = wc + j * 16 + l16;
            bf[j] = *(const bf16x8*)(Bt + r * 32 + ((quad ^ ((r >> 1) & 3)) * 8));
        }
#pragma unroll
        for (int i = 0; i < 4; i++)
#pragma unroll
            for (int j = 0; j < 4; j++)
                acc[i][j] = MFMA16(af[i], bf[j], acc[i][j]);
        cur = cur < 2 ? cur + 1 : 0;
    }
    __syncthreads();  // full drain before epilogue overlays buffers

    const float* bias = which == 0 ? bq : (which == 1 ? bk : bv);
    float sc = which == 0 ? (0.125f * 1.44269504f) : 1.0f;  // 1/sqrt(HD)*log2e
    if (which == 2) {
        for (int j = 0; j < 4; j++) {
            float bias_v = bias[n0 + wc + j * 16 + l16];
            for (int i = 0; i < 4; i++) {
                ushort4 pk;
                pk.x = f2b(acc[i][j].x + bias_v);
                pk.y = f2b(acc[i][j].y + bias_v);
                pk.z = f2b(acc[i][j].z + bias_v);
                pk.w = f2b(acc[i][j].w + bias_v);
                *(ushort4*)(Ct + (wc + j * 16 + l16) * 136 + wr + i * 16 + quad * 4) = pk;
            }
        }
    } else {
        for (int j = 0; j < 4; j++) {
            float bias_v = bias[n0 + wc + j * 16 + l16];
            int col = wc + j * 16 + l16;
            for (int i = 0; i < 4; i++) {
                int rb = wr + i * 16 + quad * 4;
                Ct[(rb + 0) * 136 + col] = f2b((acc[i][j].x + bias_v) * sc);
                Ct[(rb + 1) * 136 + col] = f2b((acc[i][j].y + bias_v) * sc);
                Ct[(rb + 2) * 136 + col] = f2b((acc[i][j].z + bias_v) * sc);
                Ct[(rb + 3) * 136 + col] = f2b((acc[i][j].w + bias_v) * sc);
            }
        }
    }
    __syncthreads();
    for (int r = 0; r < 8; r++) {
        int idx = r * 256 + t;
        int row = idx >> 4, c8 = (idx & 15) * 8;
        uint4 val = *(const uint4*)(Ct + row * 136 + c8);
        if (which == 2) {
            int col = n0 + row, h = col >> 6, d = col & 63;
            int tok = m0 + c8, b = tok >> 11, s = tok & 2047;
            *(uint4*)(vt_ws + ((size_t)(b * 16 + h) * 64 + d) * 2048 + s) = val;
        } else {
            int tok = m0 + row, b = tok >> 11, s = tok & 2047;
            int col = n0 + c8, h = col >> 6, d = col & 63;
            ushort_t* base = which == 0 ? q_ws : k_ws;
            *(uint4*)(base + ((size_t)(b * 16 + h) * 2048 + s) * 64 + d) = val;
        }
    }
}

// ---------------- flash attention (EXACT R6: measured 92.4us) ---------------
__global__ __launch_bounds__(256, 2) void attn_k(
    const ushort_t* __restrict__ q_ws, const ushort_t* __restrict__ k_ws,
    const ushort_t* __restrict__ vt_ws, const float* __restrict__ mask,
    float* __restrict__ out) {
    __shared__ __align__(16) char smraw[40960];  // 2x16KB K/V dbuf + 8KB mask
    float* Ow = (float*)smraw;                   // epilogue overlay [128][65]
    const float* Mf = (const float*)(smraw + 32768);  // mask row [2048] f32

    int bh = blockIdx.y, b = bh >> 4, h = bh & 15;
    int q0 = blockIdx.x * 256;
    int t = threadIdx.x, lane = t & 63, w = t >> 6;
    int l31 = lane & 31, hi = lane >> 5;
    const ushort_t* Q = q_ws + (size_t)bh * 2048 * 64;
    const ushort_t* K = k_ws + (size_t)bh * 2048 * 64;
    const ushort_t* Vt = vt_ws + (size_t)bh * 64 * 2048;
    const float* mrow = mask + b * 2048;

    bf16x8 qf[2][4];
#pragma unroll
    for (int qg = 0; qg < 2; qg++)
#pragma unroll
        for (int cs = 0; cs < 4; cs++)
            qf[qg][cs] = *(const bf16x8*)(
                Q + (size_t)(q0 + w * 64 + qg * 32 + l31) * 64 + cs * 16 + hi * 8);
    int co[4];
#pragma unroll
    for (int cs = 0; cs < 4; cs++) co[cs] = ((cs * 2 + hi) ^ (l31 & 7)) * 8;

    f32x16 o00 = {}, o01 = {}, o10 = {}, o11 = {};
    float rs0 = 0.f, rs1 = 0.f;

    auto stage = [&](int buf, int t0) {
        ushort_t* Kb = (ushort_t*)smraw + buf * 8192;  // 16384 B per buffer
#pragma unroll
        for (int it = 0; it < 2; it++) {
            int idx = it * 256 + t;
            int row = idx >> 3, ch = idx & 7;
            int sch = (ch ^ (row & 7)) * 8;
            gld_lds16(K + (size_t)(t0 + row) * 64 + sch, Kb + idx * 8);
            gld_lds16(Vt + (size_t)row * 2048 + t0 + sch, Kb + 4096 + idx * 8);
        }
    };

    // prologue: stage mask row (8KB) + first K/V tile
    {
        char* Mb = smraw + 32768;
#pragma unroll
        for (int it = 0; it < 2; it++) {
            int idx = it * 256 + t;
            gld_lds16(mrow + idx * 4, Mb + idx * 16);
        }
    }
    stage(0, 0);
    asm volatile("s_waitcnt vmcnt(0)" ::: "memory");
    __syncthreads();
    int cur = 0;

    for (int t0 = 0; t0 < 2048; t0 += 64) {
        if (t0 + 64 < 2048) stage(cur ^ 1, t0 + 64);  // prefetch next tile
        const ushort_t* Kl = (const ushort_t*)smraw + cur * 8192;
        const ushort_t* Vtl = Kl + 4096;

        // S^T = K · Q^T for both q-groups (K frags shared)
        f32x16 s00 = {}, s01 = {}, s10 = {}, s11 = {};
#pragma unroll
        for (int cs = 0; cs < 4; cs++) {
            bf16x8 k0 = *(const bf16x8*)(Kl + l31 * 64 + co[cs]);
            bf16x8 k1 = *(const bf16x8*)(Kl + (32 + l31) * 64 + co[cs]);
            s00 = MFMA32(k0, qf[0][cs], s00);
            s01 = MFMA32(k1, qf[0][cs], s01);
            s10 = MFMA32(k0, qf[1][cs], s10);
            s11 = MFMA32(k1, qf[1][cs], s11);
        }

        // exp2 + pack; P^T B-frags are lane-local under kappa permutation.
        bf16x8 pfr[2][4];
#pragma unroll
        for (int qg = 0; qg < 2; qg++) {
            const f32x16& sa = qg ? s10 : s00;
            const f32x16& sb = qg ? s11 : s01;
            u32 pa[8], pb[8];
            float rst = 0.f;
#pragma unroll
            for (int i = 0; i < 4; i++) {
                float4 bm = *(const float4*)(Mf + t0 + 8 * i + 4 * hi);
                float e0 = fexp2(fmaf(bm.x, 1.44269504f, sa[4 * i + 0]));
                float e1 = fexp2(fmaf(bm.y, 1.44269504f, sa[4 * i + 1]));
                float e2 = fexp2(fmaf(bm.z, 1.44269504f, sa[4 * i + 2]));
                float e3 = fexp2(fmaf(bm.w, 1.44269504f, sa[4 * i + 3]));
                rst += (e0 + e1) + (e2 + e3);
                pa[2 * i] = pkpair(e0, e1);
                pa[2 * i + 1] = pkpair(e2, e3);
            }
#pragma unroll
            for (int i = 0; i < 4; i++) {
                float4 bm = *(const float4*)(Mf + t0 + 32 + 8 * i + 4 * hi);
                float e0 = fexp2(fmaf(bm.x, 1.44269504f, sb[4 * i + 0]));
                float e1 = fexp2(fmaf(bm.y, 1.44269504f, sb[4 * i + 1]));
                float e2 = fexp2(fmaf(bm.z, 1.44269504f, sb[4 * i + 2]));
                float e3 = fexp2(fmaf(bm.w, 1.44269504f, sb[4 * i + 3]));
                rst += (e0 + e1) + (e2 + e3);
                pb[2 * i] = pkpair(e0, e1);
                pb[2 * i + 1] = pkpair(e2, e3);
            }
            if (qg == 0) rs0 += rst; else rs1 += rst;
            pfr[qg][0] = mk8(pa[0], pa[1], pa[2], pa[3]);
            pfr[qg][1] = mk8(pa[4], pa[5], pa[6], pa[7]);
            pfr[qg][2] = mk8(pb[0], pb[1], pb[2], pb[3]);
            pfr[qg][3] = mk8(pb[4], pb[5], pb[6], pb[7]);
        }

        // O^T += V^T · P^T (kappa order on both operands)
#pragma unroll
        for (int cs = 0; cs < 4; cs++) {
            int b0 = ((2 * cs) ^ (l31 & 7)) * 8 + 4 * hi;
            int b1 = ((2 * cs + 1) ^ (l31 & 7)) * 8 + 4 * hi;
            bf16x8 v0 = cat8(*(const bf16x4*)(Vtl + l31 * 64 + b0),
                             *(const bf16x4*)(Vtl + l31 * 64 + b1));
            bf16x8 v1 = cat8(*(const bf16x4*)(Vtl + (32 + l31) * 64 + b0),
                             *(const bf16x4*)(Vtl + (32 + l31) * 64 + b1));
            o00 = MFMA32(v0, pfr[0][cs], o00);
            o01 = MFMA32(v1, pfr[0][cs], o01);
            o10 = MFMA32(v0, pfr[1][cs], o10);
            o11 = MFMA32(v1, pfr[1][cs], o11);
        }

        asm volatile("s_waitcnt vmcnt(0)" ::: "memory");
        __syncthreads();
        cur ^= 1;
    }
    rs0 += __shfl_xor(rs0, 32, 64);
    rs1 += __shfl_xor(rs1, 32, 64);
    float inv0 = 1.f / rs0, inv1 = 1.f / rs1;
    // epilogue: per q-group, O^T -> LDS transpose -> coalesced f32x4 stores
#pragma unroll
    for (int qg = 0; qg < 2; qg++) {
        float inv = qg ? inv1 : inv0;
        const f32x16& a0 = qg ? o10 : o00;
        const f32x16& a1 = qg ? o11 : o01;
#pragma unroll
        for (int g = 0; g < 4; g++) {
            f32x4 c0, c1;
#pragma unroll
            for (int r = 0; r < 4; r++) {
                c0[r] = a0[4 * g + r] * inv;
                c1[r] = a1[4 * g + r] * inv;
            }
            *(f32x4*)(Ow + (w * 32 + l31) * 65 + 8 * g + 4 * hi) = c0;
            *(f32x4*)(Ow + (w * 32 + l31) * 65 + 32 + 8 * g + 4 * hi) = c1;
        }
        __syncthreads();
#pragma unroll
        for (int cc = 0; cc < 8; cc++) {
            int c = cc * 256 + t;
            int row = c >> 4, seg = (c & 15) * 4;
            f32x4 vv = *(const f32x4*)(Ow + row * 65 + seg);
            int ql = (row >> 5) * 64 + qg * 32 + (row & 31);
            *(f32x4*)(out + ((size_t)(b * 2048 + q0 + ql)) * 1024 + h * 64 + seg) = vv;
        }
        __syncthreads();
    }
}

extern "C" void kernel_launch(void* const* d_in, const int* in_sizes, int n_in,
                              void* d_out, int out_size, void* d_ws, size_t ws_size,
                              hipStream_t stream) {
    const float* hs = (const float*)d_in[0];
    const float* mask = (const float*)d_in[1];
    const float* wq = (const float*)d_in[2];
    const float* bq = (const float*)d_in[3];
    const float* wk = (const float*)d_in[4];
    const float* bk = (const float*)d_in[5];
    const float* wv = (const float*)d_in[6];
    const float* bv = (const float*)d_in[7];
    float* out = (float*)d_out;
    char* ws = (char*)d_ws;
    ushort_t* hs_b = (ushort_t*)ws;
    ushort_t* w_b = (ushort_t*)(ws + 16777216);
    ushort_t* q_ws = (ushort_t*)(ws + 23068672);
    ushort_t* k_ws = (ushort_t*)(ws + 39845888);
    ushort_t* vt_ws = (ushort_t*)(ws + 56623104);

    convert_k<<<5632, 256, 0, stream>>>(hs, wq, wk, wv, hs_b, w_b);
    qkv_gemm<<<dim3(64, 8, 3), 256, 0, stream>>>(hs_b, w_b, bq, bk, bv, q_ws, k_ws, vt_ws);
    attn_k<<<dim3(8, 64), 256, 0, stream>>>(q_ws, k_ws, vt_ws, mask, out);
}